// Round 18
// baseline (128.802 us; speedup 1.0000x reference)
//
#include <hip/hip_runtime.h>
#include <math.h>

#define C_DIM 1024
#define B_SZ 2
#define N_SEQ 2048
#define M_ROWS (B_SZ * N_SEQ)   // 4096
#define KDIM 1024
#define G1_SLOT 10240           // ushorts per 20KB gemm1 slot (A 8KB + B 12KB)
#define G2_SLOT 6144            // ushorts per 12KB gemm2 slot (A 4KB + B 8KB)

typedef float  f32x4   __attribute__((ext_vector_type(4)));
typedef short  bf16x8  __attribute__((ext_vector_type(8)));
typedef short  short4v __attribute__((ext_vector_type(4)));
typedef short  short8v __attribute__((ext_vector_type(8)));

__device__ __forceinline__ float elu1(float v) {
    return v > 0.f ? v + 1.f : expf(v);
}

__device__ __forceinline__ ushort f2bf(float f) {
    union { float f; unsigned u; } x; x.f = f;
    unsigned r = (x.u + 0x7fffu + ((x.u >> 16) & 1u)) >> 16;  // RNE
    return (ushort)r;
}
__device__ __forceinline__ float bf2f(ushort b) {
    union { unsigned u; float f; } x; x.u = ((unsigned)b) << 16;
    return x.f;
}

#define VMCNT(n) asm volatile("s_waitcnt vmcnt(" #n ")" ::: "memory")
// Fence + barrier: all waves' outstanding LDS reads DELIVERED before any wave
// passes the barrier (compiler may sink MFMA lgkm waits past a raw s_barrier
// -> slot-overwrite race, R14 failure).
#define LGKMBAR do {                                                  \
        asm volatile("s_waitcnt lgkmcnt(0)" ::: "memory");            \
        __builtin_amdgcn_sched_barrier(0);                            \
        __builtin_amdgcn_s_barrier();                                 \
    } while (0)

__device__ __forceinline__ void gl16(const ushort* g, ushort* l) {
    __builtin_amdgcn_global_load_lds(
        (const __attribute__((address_space(1))) unsigned int*)g,
        (__attribute__((address_space(3))) unsigned int*)l,
        16, 0, 0);
}

// ---------------------------------------------------------------------------
// fp32 -> bf16 (hi only, RNE) for x, [Wq;Wkv], Wo; also zeroes the 32
// per-bh reduction counters (re-zeroed every call -> deterministic replay).
// ---------------------------------------------------------------------------
__global__ __launch_bounds__(256)
void split_all_kernel(const float* __restrict__ x, const float* __restrict__ Wq,
                      const float* __restrict__ Wkv, const float* __restrict__ Wo,
                      ushort* __restrict__ xhi, ushort* __restrict__ Whi,
                      ushort* __restrict__ Wohi, int* __restrict__ counters)
{
    const int i = blockIdx.x * 256 + threadIdx.x;   // 0..1048575
    if (i < 32) counters[i] = 0;
    const float* src; ushort* dh; int off;
    if (i < 524288)        { src = x;   dh = xhi;  off = i; }
    else if (i < 655360)   { src = Wq;  dh = Whi;  off = i - 524288; }
    else if (i < 917504)   { src = Wkv; dh = Whi + (1u << 20); off = i - 655360; }
    else                   { src = Wo;  dh = Wohi; off = i - 917504; }

    const float4 a = ((const float4*)src)[off * 2];
    const float4 b = ((const float4*)src)[off * 2 + 1];
    const float v[8] = {a.x, a.y, a.z, a.w, b.x, b.y, b.z, b.w};
    ushort hv[8];
    #pragma unroll
    for (int j = 0; j < 8; ++j) hv[j] = f2bf(v[j]);
    short8v H = {(short)hv[0],(short)hv[1],(short)hv[2],(short)hv[3],
                 (short)hv[4],(short)hv[5],(short)hv[6],(short)hv[7]};
    *(short8v*)&dh[(size_t)off * 8] = H;
}

// ---------------------------------------------------------------------------
// GEMM1: QKV(bf16) = x @ [Wq;Wkv]^T (3072 cols), single-term bf16.
// 128x192 tile, BK=32, 4 waves (2x2), wave 64x96. Grid 512 -> 2 blocks/CU
// (80KB). 1 LGKMBAR/kt, 4-slot rotation, depth-3 (vmcnt(10); edges 5/0).
// XCD swizzle: 8m x 8n rectangle per XCD (5.3 MB working set vs 7.4 for
// the stripe layout) to cut B-panel L2 thrash. elu1 on cols<2048; V raw.
// ---------------------------------------------------------------------------
__global__ __launch_bounds__(256, 2)
void gemm1_kernel(const ushort* __restrict__ Ahi, const ushort* __restrict__ Bhi,
                  ushort* __restrict__ dst)
{
    extern __shared__ ushort smem[];   // 4 slots x 10240 ushorts (80 KB)

    const int bid = blockIdx.x;
    const int r   = bid & 7;           // XCD (round-robin dispatch)
    const int ii  = bid >> 3;          // 0..63 within XCD
    const int m0  = ((r >> 1) * 8 + (ii >> 3)) * 128;   // 32 m-tiles
    const int n0  = ((r & 1) * 8 + (ii & 7)) * 192;     // 16 n-tiles

    const int t    = threadIdx.x;
    const int lane = t & 63;
    const int w    = t >> 6;       // 0..3
    const int wr   = w >> 1;       // 0..1  (M half, 64 rows)
    const int wc   = w & 1;        // 0..1  (N half, 96 cols)

    const int gch     = (t & 3) ^ ((t >> 3) & 3);
    const size_t rowA  = (size_t)(m0 + (t >> 2)) * KDIM + gch * 8;   // A rows 0..63
    const size_t rowA2 = rowA + (size_t)64 * KDIM;                   // 64..127
    const size_t rowB  = (size_t)(n0 + (t >> 2)) * KDIM + gch * 8;   // B rows 0..63
    const size_t rowB2 = rowB + (size_t)64 * KDIM;                   // 64..127
    const size_t rowB3 = rowB + (size_t)128 * KDIM;                  // 128..191
    const int wl      = w * 512;

    const int frow = lane & 15;
    const int cc   = (lane >> 4) ^ ((lane >> 1) & 3);
    const int aoff = (wr * 64 + frow) * 32 + cc * 8;
    const int boff = 4096 + (wc * 96 + frow) * 32 + cc * 8;

    f32x4 acc[4][6];
    #pragma unroll
    for (int mi = 0; mi < 4; ++mi)
        #pragma unroll
        for (int nj = 0; nj < 6; ++nj)
            acc[mi][nj] = (f32x4){0.f, 0.f, 0.f, 0.f};

    #define STAGE1(slotp, koff)                                              \
        do {                                                                 \
            ushort* sl_ = (slotp);                                           \
            gl16(Ahi + rowA  + (koff), sl_ + wl);                            \
            gl16(Ahi + rowA2 + (koff), sl_ + 2048 + wl);                     \
            gl16(Bhi + rowB  + (koff), sl_ + 4096 + wl);                     \
            gl16(Bhi + rowB2 + (koff), sl_ + 6144 + wl);                     \
            gl16(Bhi + rowB3 + (koff), sl_ + 8192 + wl);                     \
        } while (0)

    // prologue: kt0->slot0, kt1->slot1, kt2->slot2  (15 loads in flight)
    STAGE1(smem, 0);
    STAGE1(smem + G1_SLOT, 32);
    STAGE1(smem + 2 * G1_SLOT, 64);

    #pragma unroll 1
    for (int kt = 0; kt < 32; ++kt) {
        ushort* sh = smem + (kt & 3) * G1_SLOT;

        if (kt <= 29) { VMCNT(10); } else if (kt == 30) { VMCNT(5); } else { VMCNT(0); }
        LGKMBAR;   // all waves' kt-1 reads DELIVERED before slot reuse
        if (kt <= 28) STAGE1(smem + ((kt + 3) & 3) * G1_SLOT, (kt + 3) * 32);

        bf16x8 ah[4], bh[6];
        #pragma unroll
        for (int mi = 0; mi < 4; ++mi)
            ah[mi] = *(const bf16x8*)(sh + aoff + mi * 512);
        #pragma unroll
        for (int nj = 0; nj < 6; ++nj)
            bh[nj] = *(const bf16x8*)(sh + boff + nj * 512);
        __builtin_amdgcn_s_setprio(1);
        #pragma unroll
        for (int mi = 0; mi < 4; ++mi)
            #pragma unroll
            for (int nj = 0; nj < 6; ++nj)
                acc[mi][nj] = __builtin_amdgcn_mfma_f32_16x16x32_bf16(
                    ah[mi], bh[nj], acc[mi][nj], 0, 0, 0);
        __builtin_amdgcn_s_setprio(0);
    }
    #undef STAGE1

    const int erow  = m0 + wr * 64 + (lane >> 4) * 4;
    const int ecol0 = n0 + wc * 96 + frow;
    #pragma unroll
    for (int mi = 0; mi < 4; ++mi) {
        #pragma unroll
        for (int j = 0; j < 4; ++j) {
            const int row = erow + mi * 16 + j;
            #pragma unroll
            for (int nj = 0; nj < 6; ++nj) {
                const int col = ecol0 + nj * 16;
                float v = acc[mi][nj][j];
                if (col < 2048) v = elu1(v);   // Q,K get elu1; V raw
                dst[(size_t)row * 3072 + col] = f2bf(v);
            }
        }
    }
}

// ---------------------------------------------------------------------------
// GEMM2: out = O1 @ Wo^T + bo, single-term bf16. 64x128 tile, BK=32,
// 4 waves (1M x 4N), wave 64x32. Grid 512 -> 2 blocks/CU (48KB).
// 1 LGKMBAR/kt, 4-slot rotation, depth-3 (vmcnt(6); edges 3/0).
// ---------------------------------------------------------------------------
__global__ __launch_bounds__(256, 2)
void gemm2_kernel(const ushort* __restrict__ O1, const ushort* __restrict__ Wo,
                  const float* __restrict__ bias, float* __restrict__ dst)
{
    __shared__ ushort smem[4 * G2_SLOT];   // 48 KB

    const int bid = blockIdx.x;
    const int wg  = (bid & 7) * 64 + (bid >> 3);    // bijective: 512 = 8*64
    const int m0  = (wg >> 3) * 64;                 // 64 m-tiles
    const int n0  = (wg & 7) * 128;                 // 8 n-tiles

    const int t    = threadIdx.x;
    const int lane = t & 63;
    const int w    = t >> 6;      // 0..3 (N quarters, 32 cols)

    const int gch     = (t & 3) ^ ((t >> 3) & 3);
    const size_t rowA  = (size_t)(m0 + (t >> 2)) * KDIM + gch * 8;   // 64 rows
    const size_t rowB  = (size_t)(n0 + (t >> 2)) * KDIM + gch * 8;   // rows 0..63
    const size_t rowB2 = rowB + (size_t)64 * KDIM;                   // 64..127
    const int wl      = w * 512;

    const int frow = lane & 15;
    const int cc   = (lane >> 4) ^ ((lane >> 1) & 3);
    const int aoff = frow * 32 + cc * 8;
    const int boff = 2048 + (w * 32 + frow) * 32 + cc * 8;

    f32x4 acc[4][2];
    #pragma unroll
    for (int mi = 0; mi < 4; ++mi)
        #pragma unroll
        for (int nj = 0; nj < 2; ++nj)
            acc[mi][nj] = (f32x4){0.f, 0.f, 0.f, 0.f};

    #define STAGE2(slotp, koff)                                              \
        do {                                                                 \
            ushort* p_ = (slotp);                                            \
            gl16(O1 + rowA  + (koff), p_ + wl);                              \
            gl16(Wo + rowB  + (koff), p_ + 2048 + wl);                       \
            gl16(Wo + rowB2 + (koff), p_ + 4096 + wl);                       \
        } while (0)

    // prologue: kt0->slot0, kt1->slot1, kt2->slot2  (9 loads in flight)
    STAGE2(smem, 0);
    STAGE2(smem + G2_SLOT, 32);
    STAGE2(smem + 2 * G2_SLOT, 64);

    #pragma unroll 1
    for (int kt = 0; kt < 32; ++kt) {
        ushort* sh = smem + (kt & 3) * G2_SLOT;

        if (kt <= 29) { VMCNT(6); } else if (kt == 30) { VMCNT(3); } else { VMCNT(0); }
        LGKMBAR;
        if (kt <= 28) STAGE2(smem + ((kt + 3) & 3) * G2_SLOT, (kt + 3) * 32);

        bf16x8 ah[4], bh[2];
        #pragma unroll
        for (int mi = 0; mi < 4; ++mi)
            ah[mi] = *(const bf16x8*)(sh + aoff + mi * 512);
        #pragma unroll
        for (int nj = 0; nj < 2; ++nj)
            bh[nj] = *(const bf16x8*)(sh + boff + nj * 512);
        __builtin_amdgcn_s_setprio(1);
        #pragma unroll
        for (int mi = 0; mi < 4; ++mi)
            #pragma unroll
            for (int nj = 0; nj < 2; ++nj)
                acc[mi][nj] = __builtin_amdgcn_mfma_f32_16x16x32_bf16(
                    ah[mi], bh[nj], acc[mi][nj], 0, 0, 0);
        __builtin_amdgcn_s_setprio(0);
    }
    #undef STAGE2

    const int erow  = m0 + (lane >> 4) * 4;
    const int ecol0 = n0 + w * 32 + frow;
    #pragma unroll
    for (int mi = 0; mi < 4; ++mi) {
        #pragma unroll
        for (int j = 0; j < 4; ++j) {
            const int row = erow + mi * 16 + j;
            #pragma unroll
            for (int nj = 0; nj < 2; ++nj) {
                const int col = ecol0 + nj * 16;
                dst[(size_t)row * 1024 + col] = acc[mi][nj][j] + bias[col];
            }
        }
    }
}

// ---------------------------------------------------------------------------
// Partial KV = K_feat^T V and ksum, per (b,h), 8-way N split; the LAST block
// per bh (device-scope atomic counter) reduces the 8 partials in fixed index
// order into KVf — value is order-deterministic regardless of which block
// performs it. Counters zeroed by split_all each call.
// ---------------------------------------------------------------------------
__global__ __launch_bounds__(256)
void kv_partial_kernel(const ushort* __restrict__ QKV, float* __restrict__ KVp,
                       float* __restrict__ KVf, int* __restrict__ counters)
{
    const int bh = blockIdx.x;   // 0..31
    const int s  = blockIdx.y;   // 0..7
    const int b  = bh >> 4;
    const int h  = bh & 15;
    const int t  = threadIdx.x;

    __shared__ float ks[16][64];
    __shared__ float vs[16][64];
    __shared__ float red[4160];
    __shared__ int last_flag;

    const int srow = t >> 4;
    const int scol = (t & 15) * 4;
    const size_t gk = (size_t)(b * N_SEQ + s * 256) * 3072 + 1024 + h * 64 + scol;
    const size_t gv = gk + 1024;

    const int rs = t >> 6;
    const int dg = (t >> 3) & 7;
    const int eg = t & 7;
    const int d0 = dg * 8;
    const int e0 = eg * 8;

    float acc[8][8];
    #pragma unroll
    for (int i = 0; i < 8; ++i)
        #pragma unroll
        for (int j = 0; j < 8; ++j) acc[i][j] = 0.f;
    float aks[8] = {0.f, 0.f, 0.f, 0.f, 0.f, 0.f, 0.f, 0.f};

    short4v kr = *(const short4v*)&QKV[gk + (size_t)srow * 3072];
    short4v vr = *(const short4v*)&QKV[gv + (size_t)srow * 3072];

    for (int it = 0; it < 16; ++it) {
        __syncthreads();
        ks[srow][scol + 0] = bf2f((ushort)kr[0]);
        ks[srow][scol + 1] = bf2f((ushort)kr[1]);
        ks[srow][scol + 2] = bf2f((ushort)kr[2]);
        ks[srow][scol + 3] = bf2f((ushort)kr[3]);
        vs[srow][scol + 0] = bf2f((ushort)vr[0]);
        vs[srow][scol + 1] = bf2f((ushort)vr[1]);
        vs[srow][scol + 2] = bf2f((ushort)vr[2]);
        vs[srow][scol + 3] = bf2f((ushort)vr[3]);
        __syncthreads();
        if (it < 15) {
            kr = *(const short4v*)&QKV[gk + (size_t)((it + 1) * 16 + srow) * 3072];
            vr = *(const short4v*)&QKV[gv + (size_t)((it + 1) * 16 + srow) * 3072];
        }
        #pragma unroll
        for (int rr = 0; rr < 4; ++rr) {
            const int r = rs * 4 + rr;
            const float4 ka = *(const float4*)&ks[r][d0];
            const float4 kb = *(const float4*)&ks[r][d0 + 4];
            const float4 va = *(const float4*)&vs[r][e0];
            const float4 vb = *(const float4*)&vs[r][e0 + 4];
            const float k8[8] = {ka.x, ka.y, ka.z, ka.w, kb.x, kb.y, kb.z, kb.w};
            const float v8[8] = {va.x, va.y, va.z, va.w, vb.x, vb.y, vb.z, vb.w};
            #pragma unroll
            for (int i = 0; i < 8; ++i)
                #pragma unroll
                for (int j = 0; j < 8; ++j)
                    acc[i][j] += k8[i] * v8[j];
            if (eg == 0) {
                #pragma unroll
                for (int i = 0; i < 8; ++i) aks[i] += k8[i];
            }
        }
    }

    // in-block rowset merge
    #pragma unroll 1
    for (int step = 1; step < 4; ++step) {
        __syncthreads();
        if (rs == step) {
            #pragma unroll
            for (int i = 0; i < 8; ++i)
                #pragma unroll
                for (int j = 0; j < 8; ++j)
                    red[(d0 + i) * 64 + e0 + j] = acc[i][j];
            if (eg == 0) {
                #pragma unroll
                for (int i = 0; i < 8; ++i) red[4096 + d0 + i] = aks[i];
            }
        }
        __syncthreads();
        if (rs == 0) {
            #pragma unroll
            for (int i = 0; i < 8; ++i)
                #pragma unroll
                for (int j = 0; j < 8; ++j)
                    acc[i][j] += red[(d0 + i) * 64 + e0 + j];
            if (eg == 0) {
                #pragma unroll
                for (int i = 0; i < 8; ++i) aks[i] += red[4096 + d0 + i];
            }
        }
    }

    if (rs == 0) {
        float* outp = KVp + ((size_t)s * 32 + bh) * 4160;
        #pragma unroll
        for (int i = 0; i < 8; ++i) {
            float4 o0 = {acc[i][0], acc[i][1], acc[i][2], acc[i][3]};
            float4 o1 = {acc[i][4], acc[i][5], acc[i][6], acc[i][7]};
            *(float4*)(outp + (d0 + i) * 64 + e0)     = o0;
            *(float4*)(outp + (d0 + i) * 64 + e0 + 4) = o1;
        }
        if (eg == 0) {
            #pragma unroll
            for (int i = 0; i < 8; ++i) outp[4096 + d0 + i] = aks[i];
        }
    }

    // last-block-per-bh reduction of the 8 partials (fixed order -> deterministic)
    __threadfence();          // make this block's partial visible device-wide
    __syncthreads();
    if (t == 0) last_flag = atomicAdd(&counters[bh], 1);
    __syncthreads();
    if (last_flag == 7) {
        __threadfence();      // acquire: other blocks' partials now visible
        for (int idx = t; idx < 4160; idx += 256) {
            float sum = 0.f;
            #pragma unroll
            for (int p = 0; p < 8; ++p)
                sum += KVp[((size_t)p * 32 + bh) * 4160 + idx];
            KVf[(size_t)bh * 4160 + idx] = sum;
        }
    }
}

// ---------------------------------------------------------------------------
// O1[n, h*64+e] = Z * sum_d q[n,d]*KV[d,e], Z = 1/(q.ksum + 1e-6).
// Q read bf16; O1 emitted single bf16.
// ---------------------------------------------------------------------------
__global__ __launch_bounds__(256)
void attn_apply_kernel(const ushort* __restrict__ QKV, const float* __restrict__ KVf,
                       ushort* __restrict__ O1)
{
    const int bh = blockIdx.x;
    const int b = bh >> 4, h = bh & 15;
    const int n0 = blockIdx.y * 16;
    const int t = threadIdx.x;
    const int r  = t >> 4;
    const int e0 = (t & 15) * 4;

    __shared__ float kvs[64][68];
    __shared__ float qs[16][68];
    __shared__ float ksums[64];

    const float* kvb = KVf + (size_t)bh * 4160;
    for (int i = t; i < 4096; i += 256)
        kvs[i >> 6][i & 63] = kvb[i];
    if (t < 64) ksums[t] = kvb[4096 + t];
    {
        const int rr = t >> 4, cc2 = (t & 15) * 4;
        short4v q4 = *(const short4v*)&QKV[(size_t)(b * N_SEQ + n0 + rr) * 3072 + h * 64 + cc2];
        qs[rr][cc2 + 0] = bf2f((ushort)q4[0]);
        qs[rr][cc2 + 1] = bf2f((ushort)q4[1]);
        qs[rr][cc2 + 2] = bf2f((ushort)q4[2]);
        qs[rr][cc2 + 3] = bf2f((ushort)q4[3]);
    }
    __syncthreads();

    float4 acc = {0.f, 0.f, 0.f, 0.f};
    float accz = 0.f;
    #pragma unroll
    for (int d = 0; d < 64; ++d) {
        const float qv = qs[r][d];
        const float4 kvv = *(const float4*)&kvs[d][e0];
        acc.x += qv * kvv.x; acc.y += qv * kvv.y;
        acc.z += qv * kvv.z; acc.w += qv * kvv.w;
        accz += qv * ksums[d];
    }
    const float Z = 1.f / (accz + 1e-6f);
    const size_t off = (size_t)(b * N_SEQ + n0 + r) * C_DIM + h * 64 + e0;
    short4v H = {(short)f2bf(acc.x * Z), (short)f2bf(acc.y * Z),
                 (short)f2bf(acc.z * Z), (short)f2bf(acc.w * Z)};
    *(short4v*)&O1[off] = H;
}

extern "C" void kernel_launch(void* const* d_in, const int* in_sizes, int n_in,
                              void* d_out, int out_size, void* d_ws, size_t ws_size,
                              hipStream_t stream)
{
    const float* x   = (const float*)d_in[0];
    const float* Wq  = (const float*)d_in[1];
    const float* Wkv = (const float*)d_in[2];
    const float* Wo  = (const float*)d_in[3];
    const float* bo  = (const float*)d_in[4];
    float* out = (float*)d_out;

    float* ws    = (float*)d_ws;
    ushort* QKVu = (ushort*)ws;                        // 4096*3072 bf16 (24 MB)
    float* KVp   = ws + (size_t)M_ROWS * 3072 / 2;     // 8*32*4160 f32
    float* KVf   = KVp + (size_t)8 * 32 * 4160;        // 32*4160
    int*   ctrs  = (int*)(KVf + 32 * 4160);            // 32 ints
    ushort* xhi  = (ushort*)(ctrs + 64);               // 4096*1024 bf16
    ushort* Whi  = xhi + (size_t)M_ROWS * 1024;        // 3072*1024 (Wq;Wkv)
    ushort* Wohi = Whi + (size_t)3072 * 1024;          // 1024*1024
    ushort* O1   = xhi;                                // alias: x dead after GEMM1

    hipFuncSetAttribute((const void*)gemm1_kernel,
                        hipFuncAttributeMaxDynamicSharedMemorySize, 81920);

    // 0. fp32 -> bf16 conversions + counter reset
    split_all_kernel<<<dim3(4096), 256, 0, stream>>>(
        x, Wq, Wkv, Wo, xhi, Whi, Wohi, ctrs);

    // 1. fused q/k/v projections, single-term bf16, bf16 output
    gemm1_kernel<<<dim3(512), 256, 81920, stream>>>(xhi, Whi, QKVu);

    // 2. KV = K^T V + ksum (8-way split; last block per bh reduces -> KVf)
    kv_partial_kernel<<<dim3(32, 8), 256, 0, stream>>>(QKVu, KVp, KVf, ctrs);

    // 3. O1 = Z * (q @ KV), bf16 out
    attn_apply_kernel<<<dim3(32, 128), 256, 0, stream>>>(QKVu, KVf, O1);

    // 4. final projection + bias (single-term bf16)
    gemm2_kernel<<<dim3(512), 256, 0, stream>>>(O1, Wohi, bo, out);
}

// Round 19
// 99.297 us; speedup vs baseline: 1.2971x; 1.2971x over previous
//
#include <hip/hip_runtime.h>
#include <math.h>

#define C_DIM 1024
#define B_SZ 2
#define N_SEQ 2048
#define M_ROWS (B_SZ * N_SEQ)   // 4096
#define KDIM 1024
#define G1_SLOT 10240           // ushorts per 20KB gemm1 slot (A 8KB + B 12KB)
#define G2_SLOT 6144            // ushorts per 12KB gemm2 slot (A 4KB + B 8KB)

typedef float  f32x4   __attribute__((ext_vector_type(4)));
typedef short  bf16x8  __attribute__((ext_vector_type(8)));
typedef short  short4v __attribute__((ext_vector_type(4)));
typedef short  short8v __attribute__((ext_vector_type(8)));

__device__ __forceinline__ float elu1(float v) {
    return v > 0.f ? v + 1.f : expf(v);
}

__device__ __forceinline__ ushort f2bf(float f) {
    union { float f; unsigned u; } x; x.f = f;
    unsigned r = (x.u + 0x7fffu + ((x.u >> 16) & 1u)) >> 16;  // RNE
    return (ushort)r;
}
__device__ __forceinline__ float bf2f(ushort b) {
    union { unsigned u; float f; } x; x.u = ((unsigned)b) << 16;
    return x.f;
}

#define VMCNT(n) asm volatile("s_waitcnt vmcnt(" #n ")" ::: "memory")
// Fence + barrier: all waves' outstanding LDS reads DELIVERED before any wave
// passes the barrier (compiler may sink MFMA lgkm waits past a raw s_barrier
// -> slot-overwrite race, R14 failure).
#define LGKMBAR do {                                                  \
        asm volatile("s_waitcnt lgkmcnt(0)" ::: "memory");            \
        __builtin_amdgcn_sched_barrier(0);                            \
        __builtin_amdgcn_s_barrier();                                 \
    } while (0)

__device__ __forceinline__ void gl16(const ushort* g, ushort* l) {
    __builtin_amdgcn_global_load_lds(
        (const __attribute__((address_space(1))) unsigned int*)g,
        (__attribute__((address_space(3))) unsigned int*)l,
        16, 0, 0);
}

// ---------------------------------------------------------------------------
// fp32 -> bf16 (hi only, RNE) for x, [Wq;Wkv], Wo. 8 elems/thread.
// ---------------------------------------------------------------------------
__global__ __launch_bounds__(256)
void split_all_kernel(const float* __restrict__ x, const float* __restrict__ Wq,
                      const float* __restrict__ Wkv, const float* __restrict__ Wo,
                      ushort* __restrict__ xhi, ushort* __restrict__ Whi,
                      ushort* __restrict__ Wohi)
{
    const int i = blockIdx.x * 256 + threadIdx.x;   // 0..1048575
    const float* src; ushort* dh; int off;
    if (i < 524288)        { src = x;   dh = xhi;  off = i; }
    else if (i < 655360)   { src = Wq;  dh = Whi;  off = i - 524288; }
    else if (i < 917504)   { src = Wkv; dh = Whi + (1u << 20); off = i - 655360; }
    else                   { src = Wo;  dh = Wohi; off = i - 917504; }

    const float4 a = ((const float4*)src)[off * 2];
    const float4 b = ((const float4*)src)[off * 2 + 1];
    const float v[8] = {a.x, a.y, a.z, a.w, b.x, b.y, b.z, b.w};
    ushort hv[8];
    #pragma unroll
    for (int j = 0; j < 8; ++j) hv[j] = f2bf(v[j]);
    short8v H = {(short)hv[0],(short)hv[1],(short)hv[2],(short)hv[3],
                 (short)hv[4],(short)hv[5],(short)hv[6],(short)hv[7]};
    *(short8v*)&dh[(size_t)off * 8] = H;
}

// ---------------------------------------------------------------------------
// GEMM1: QKV(bf16) = x @ [Wq;Wkv]^T (3072 cols), single-term bf16.
// 128x192 tile, BK=32, 4 waves (2x2), wave 64x96. Grid 512 -> 2 blocks/CU
// (80KB). 1 LGKMBAR/kt, 4-slot rotation, depth-3 (vmcnt(10); edges 5/0).
// XCD swizzle: 8m x 8n rectangle per XCD (5.3 MB working set). elu1 on
// cols<2048; V raw.
// ---------------------------------------------------------------------------
__global__ __launch_bounds__(256, 2)
void gemm1_kernel(const ushort* __restrict__ Ahi, const ushort* __restrict__ Bhi,
                  ushort* __restrict__ dst)
{
    extern __shared__ ushort smem[];   // 4 slots x 10240 ushorts (80 KB)

    const int bid = blockIdx.x;
    const int r   = bid & 7;           // XCD (round-robin dispatch)
    const int ii  = bid >> 3;          // 0..63 within XCD
    const int m0  = ((r >> 1) * 8 + (ii >> 3)) * 128;   // 32 m-tiles
    const int n0  = ((r & 1) * 8 + (ii & 7)) * 192;     // 16 n-tiles

    const int t    = threadIdx.x;
    const int lane = t & 63;
    const int w    = t >> 6;       // 0..3
    const int wr   = w >> 1;       // 0..1  (M half, 64 rows)
    const int wc   = w & 1;        // 0..1  (N half, 96 cols)

    const int gch     = (t & 3) ^ ((t >> 3) & 3);
    const size_t rowA  = (size_t)(m0 + (t >> 2)) * KDIM + gch * 8;   // A rows 0..63
    const size_t rowA2 = rowA + (size_t)64 * KDIM;                   // 64..127
    const size_t rowB  = (size_t)(n0 + (t >> 2)) * KDIM + gch * 8;   // B rows 0..63
    const size_t rowB2 = rowB + (size_t)64 * KDIM;                   // 64..127
    const size_t rowB3 = rowB + (size_t)128 * KDIM;                  // 128..191
    const int wl      = w * 512;

    const int frow = lane & 15;
    const int cc   = (lane >> 4) ^ ((lane >> 1) & 3);
    const int aoff = (wr * 64 + frow) * 32 + cc * 8;
    const int boff = 4096 + (wc * 96 + frow) * 32 + cc * 8;

    f32x4 acc[4][6];
    #pragma unroll
    for (int mi = 0; mi < 4; ++mi)
        #pragma unroll
        for (int nj = 0; nj < 6; ++nj)
            acc[mi][nj] = (f32x4){0.f, 0.f, 0.f, 0.f};

    #define STAGE1(slotp, koff)                                              \
        do {                                                                 \
            ushort* sl_ = (slotp);                                           \
            gl16(Ahi + rowA  + (koff), sl_ + wl);                            \
            gl16(Ahi + rowA2 + (koff), sl_ + 2048 + wl);                     \
            gl16(Bhi + rowB  + (koff), sl_ + 4096 + wl);                     \
            gl16(Bhi + rowB2 + (koff), sl_ + 6144 + wl);                     \
            gl16(Bhi + rowB3 + (koff), sl_ + 8192 + wl);                     \
        } while (0)

    // prologue: kt0->slot0, kt1->slot1, kt2->slot2  (15 loads in flight)
    STAGE1(smem, 0);
    STAGE1(smem + G1_SLOT, 32);
    STAGE1(smem + 2 * G1_SLOT, 64);

    #pragma unroll 1
    for (int kt = 0; kt < 32; ++kt) {
        ushort* sh = smem + (kt & 3) * G1_SLOT;

        if (kt <= 29) { VMCNT(10); } else if (kt == 30) { VMCNT(5); } else { VMCNT(0); }
        LGKMBAR;   // all waves' kt-1 reads DELIVERED before slot reuse
        if (kt <= 28) STAGE1(smem + ((kt + 3) & 3) * G1_SLOT, (kt + 3) * 32);

        bf16x8 ah[4], bh[6];
        #pragma unroll
        for (int mi = 0; mi < 4; ++mi)
            ah[mi] = *(const bf16x8*)(sh + aoff + mi * 512);
        #pragma unroll
        for (int nj = 0; nj < 6; ++nj)
            bh[nj] = *(const bf16x8*)(sh + boff + nj * 512);
        __builtin_amdgcn_s_setprio(1);
        #pragma unroll
        for (int mi = 0; mi < 4; ++mi)
            #pragma unroll
            for (int nj = 0; nj < 6; ++nj)
                acc[mi][nj] = __builtin_amdgcn_mfma_f32_16x16x32_bf16(
                    ah[mi], bh[nj], acc[mi][nj], 0, 0, 0);
        __builtin_amdgcn_s_setprio(0);
    }
    #undef STAGE1

    const int erow  = m0 + wr * 64 + (lane >> 4) * 4;
    const int ecol0 = n0 + wc * 96 + frow;
    #pragma unroll
    for (int mi = 0; mi < 4; ++mi) {
        #pragma unroll
        for (int j = 0; j < 4; ++j) {
            const int row = erow + mi * 16 + j;
            #pragma unroll
            for (int nj = 0; nj < 6; ++nj) {
                const int col = ecol0 + nj * 16;
                float v = acc[mi][nj][j];
                if (col < 2048) v = elu1(v);   // Q,K get elu1; V raw
                dst[(size_t)row * 3072 + col] = f2bf(v);
            }
        }
    }
}

// ---------------------------------------------------------------------------
// GEMM2: out = O1 @ Wo^T + bo, single-term bf16. 64x128 tile, BK=32,
// 4 waves (1M x 4N), wave 64x32. Grid 512 -> 2 blocks/CU (48KB).
// 1 LGKMBAR/kt, 4-slot rotation, depth-3 (vmcnt(6); edges 3/0).
// ---------------------------------------------------------------------------
__global__ __launch_bounds__(256, 2)
void gemm2_kernel(const ushort* __restrict__ O1, const ushort* __restrict__ Wo,
                  const float* __restrict__ bias, float* __restrict__ dst)
{
    __shared__ ushort smem[4 * G2_SLOT];   // 48 KB

    const int bid = blockIdx.x;
    const int wg  = (bid & 7) * 64 + (bid >> 3);    // bijective: 512 = 8*64
    const int m0  = (wg >> 3) * 64;                 // 64 m-tiles
    const int n0  = (wg & 7) * 128;                 // 8 n-tiles

    const int t    = threadIdx.x;
    const int lane = t & 63;
    const int w    = t >> 6;      // 0..3 (N quarters, 32 cols)

    const int gch     = (t & 3) ^ ((t >> 3) & 3);
    const size_t rowA  = (size_t)(m0 + (t >> 2)) * KDIM + gch * 8;   // 64 rows
    const size_t rowB  = (size_t)(n0 + (t >> 2)) * KDIM + gch * 8;   // rows 0..63
    const size_t rowB2 = rowB + (size_t)64 * KDIM;                   // 64..127
    const int wl      = w * 512;

    const int frow = lane & 15;
    const int cc   = (lane >> 4) ^ ((lane >> 1) & 3);
    const int aoff = frow * 32 + cc * 8;
    const int boff = 2048 + (w * 32 + frow) * 32 + cc * 8;

    f32x4 acc[4][2];
    #pragma unroll
    for (int mi = 0; mi < 4; ++mi)
        #pragma unroll
        for (int nj = 0; nj < 2; ++nj)
            acc[mi][nj] = (f32x4){0.f, 0.f, 0.f, 0.f};

    #define STAGE2(slotp, koff)                                              \
        do {                                                                 \
            ushort* p_ = (slotp);                                            \
            gl16(O1 + rowA  + (koff), p_ + wl);                              \
            gl16(Wo + rowB  + (koff), p_ + 2048 + wl);                       \
            gl16(Wo + rowB2 + (koff), p_ + 4096 + wl);                       \
        } while (0)

    // prologue: kt0->slot0, kt1->slot1, kt2->slot2  (9 loads in flight)
    STAGE2(smem, 0);
    STAGE2(smem + G2_SLOT, 32);
    STAGE2(smem + 2 * G2_SLOT, 64);

    #pragma unroll 1
    for (int kt = 0; kt < 32; ++kt) {
        ushort* sh = smem + (kt & 3) * G2_SLOT;

        if (kt <= 29) { VMCNT(6); } else if (kt == 30) { VMCNT(3); } else { VMCNT(0); }
        LGKMBAR;
        if (kt <= 28) STAGE2(smem + ((kt + 3) & 3) * G2_SLOT, (kt + 3) * 32);

        bf16x8 ah[4], bh[2];
        #pragma unroll
        for (int mi = 0; mi < 4; ++mi)
            ah[mi] = *(const bf16x8*)(sh + aoff + mi * 512);
        #pragma unroll
        for (int nj = 0; nj < 2; ++nj)
            bh[nj] = *(const bf16x8*)(sh + boff + nj * 512);
        __builtin_amdgcn_s_setprio(1);
        #pragma unroll
        for (int mi = 0; mi < 4; ++mi)
            #pragma unroll
            for (int nj = 0; nj < 2; ++nj)
                acc[mi][nj] = __builtin_amdgcn_mfma_f32_16x16x32_bf16(
                    ah[mi], bh[nj], acc[mi][nj], 0, 0, 0);
        __builtin_amdgcn_s_setprio(0);
    }
    #undef STAGE2

    const int erow  = m0 + (lane >> 4) * 4;
    const int ecol0 = n0 + w * 32 + frow;
    #pragma unroll
    for (int mi = 0; mi < 4; ++mi) {
        #pragma unroll
        for (int j = 0; j < 4; ++j) {
            const int row = erow + mi * 16 + j;
            #pragma unroll
            for (int nj = 0; nj < 2; ++nj) {
                const int col = ecol0 + nj * 16;
                dst[(size_t)row * 1024 + col] = acc[mi][nj][j] + bias[col];
            }
        }
    }
}

// ---------------------------------------------------------------------------
// Partial KV = K_feat^T V and ksum, per (b,h), 8-way N split (256 rows each).
// QKV bf16: stage short4v, convert to f32 in LDS; compute f32.
// ---------------------------------------------------------------------------
__global__ __launch_bounds__(256)
void kv_partial_kernel(const ushort* __restrict__ QKV, float* __restrict__ KVp)
{
    const int bh = blockIdx.x;   // 0..31
    const int s  = blockIdx.y;   // 0..7
    const int b  = bh >> 4;
    const int h  = bh & 15;
    const int t  = threadIdx.x;

    __shared__ float ks[16][64];
    __shared__ float vs[16][64];
    __shared__ float red[4160];

    const int srow = t >> 4;
    const int scol = (t & 15) * 4;
    const size_t gk = (size_t)(b * N_SEQ + s * 256) * 3072 + 1024 + h * 64 + scol;
    const size_t gv = gk + 1024;

    const int rs = t >> 6;
    const int dg = (t >> 3) & 7;
    const int eg = t & 7;
    const int d0 = dg * 8;
    const int e0 = eg * 8;

    float acc[8][8];
    #pragma unroll
    for (int i = 0; i < 8; ++i)
        #pragma unroll
        for (int j = 0; j < 8; ++j) acc[i][j] = 0.f;
    float aks[8] = {0.f, 0.f, 0.f, 0.f, 0.f, 0.f, 0.f, 0.f};

    short4v kr = *(const short4v*)&QKV[gk + (size_t)srow * 3072];
    short4v vr = *(const short4v*)&QKV[gv + (size_t)srow * 3072];

    for (int it = 0; it < 16; ++it) {
        __syncthreads();
        ks[srow][scol + 0] = bf2f((ushort)kr[0]);
        ks[srow][scol + 1] = bf2f((ushort)kr[1]);
        ks[srow][scol + 2] = bf2f((ushort)kr[2]);
        ks[srow][scol + 3] = bf2f((ushort)kr[3]);
        vs[srow][scol + 0] = bf2f((ushort)vr[0]);
        vs[srow][scol + 1] = bf2f((ushort)vr[1]);
        vs[srow][scol + 2] = bf2f((ushort)vr[2]);
        vs[srow][scol + 3] = bf2f((ushort)vr[3]);
        __syncthreads();
        if (it < 15) {
            kr = *(const short4v*)&QKV[gk + (size_t)((it + 1) * 16 + srow) * 3072];
            vr = *(const short4v*)&QKV[gv + (size_t)((it + 1) * 16 + srow) * 3072];
        }
        #pragma unroll
        for (int rr = 0; rr < 4; ++rr) {
            const int r = rs * 4 + rr;
            const float4 ka = *(const float4*)&ks[r][d0];
            const float4 kb = *(const float4*)&ks[r][d0 + 4];
            const float4 va = *(const float4*)&vs[r][e0];
            const float4 vb = *(const float4*)&vs[r][e0 + 4];
            const float k8[8] = {ka.x, ka.y, ka.z, ka.w, kb.x, kb.y, kb.z, kb.w};
            const float v8[8] = {va.x, va.y, va.z, va.w, vb.x, vb.y, vb.z, vb.w};
            #pragma unroll
            for (int i = 0; i < 8; ++i)
                #pragma unroll
                for (int j = 0; j < 8; ++j)
                    acc[i][j] += k8[i] * v8[j];
            if (eg == 0) {
                #pragma unroll
                for (int i = 0; i < 8; ++i) aks[i] += k8[i];
            }
        }
    }

    #pragma unroll 1
    for (int step = 1; step < 4; ++step) {
        __syncthreads();
        if (rs == step) {
            #pragma unroll
            for (int i = 0; i < 8; ++i)
                #pragma unroll
                for (int j = 0; j < 8; ++j)
                    red[(d0 + i) * 64 + e0 + j] = acc[i][j];
            if (eg == 0) {
                #pragma unroll
                for (int i = 0; i < 8; ++i) red[4096 + d0 + i] = aks[i];
            }
        }
        __syncthreads();
        if (rs == 0) {
            #pragma unroll
            for (int i = 0; i < 8; ++i)
                #pragma unroll
                for (int j = 0; j < 8; ++j)
                    acc[i][j] += red[(d0 + i) * 64 + e0 + j];
            if (eg == 0) {
                #pragma unroll
                for (int i = 0; i < 8; ++i) aks[i] += red[4096 + d0 + i];
            }
        }
    }

    if (rs == 0) {
        float* outp = KVp + ((size_t)s * 32 + bh) * 4160;
        #pragma unroll
        for (int i = 0; i < 8; ++i) {
            float4 o0 = {acc[i][0], acc[i][1], acc[i][2], acc[i][3]};
            float4 o1 = {acc[i][4], acc[i][5], acc[i][6], acc[i][7]};
            *(float4*)(outp + (d0 + i) * 64 + e0)     = o0;
            *(float4*)(outp + (d0 + i) * 64 + e0 + 4) = o1;
        }
        if (eg == 0) {
            #pragma unroll
            for (int i = 0; i < 8; ++i) outp[4096 + d0 + i] = aks[i];
        }
    }
}

__global__ __launch_bounds__(256)
void kv_reduce_kernel(const float* __restrict__ KVp, float* __restrict__ KVf)
{
    const int idx = blockIdx.x * 256 + threadIdx.x;
    if (idx < 32 * 4160) {
        float s = 0.f;
        #pragma unroll
        for (int i = 0; i < 8; ++i) s += KVp[(size_t)i * (32 * 4160) + idx];
        KVf[idx] = s;
    }
}

// ---------------------------------------------------------------------------
// O1[n, h*64+e] = Z * sum_d q[n,d]*KV[d,e], Z = 1/(q.ksum + 1e-6).
// Q read bf16; O1 emitted single bf16.
// ---------------------------------------------------------------------------
__global__ __launch_bounds__(256)
void attn_apply_kernel(const ushort* __restrict__ QKV, const float* __restrict__ KVf,
                       ushort* __restrict__ O1)
{
    const int bh = blockIdx.x;
    const int b = bh >> 4, h = bh & 15;
    const int n0 = blockIdx.y * 16;
    const int t = threadIdx.x;
    const int r  = t >> 4;
    const int e0 = (t & 15) * 4;

    __shared__ float kvs[64][68];
    __shared__ float qs[16][68];
    __shared__ float ksums[64];

    const float* kvb = KVf + (size_t)bh * 4160;
    for (int i = t; i < 4096; i += 256)
        kvs[i >> 6][i & 63] = kvb[i];
    if (t < 64) ksums[t] = kvb[4096 + t];
    {
        const int rr = t >> 4, cc2 = (t & 15) * 4;
        short4v q4 = *(const short4v*)&QKV[(size_t)(b * N_SEQ + n0 + rr) * 3072 + h * 64 + cc2];
        qs[rr][cc2 + 0] = bf2f((ushort)q4[0]);
        qs[rr][cc2 + 1] = bf2f((ushort)q4[1]);
        qs[rr][cc2 + 2] = bf2f((ushort)q4[2]);
        qs[rr][cc2 + 3] = bf2f((ushort)q4[3]);
    }
    __syncthreads();

    float4 acc = {0.f, 0.f, 0.f, 0.f};
    float accz = 0.f;
    #pragma unroll
    for (int d = 0; d < 64; ++d) {
        const float qv = qs[r][d];
        const float4 kvv = *(const float4*)&kvs[d][e0];
        acc.x += qv * kvv.x; acc.y += qv * kvv.y;
        acc.z += qv * kvv.z; acc.w += qv * kvv.w;
        accz += qv * ksums[d];
    }
    const float Z = 1.f / (accz + 1e-6f);
    const size_t off = (size_t)(b * N_SEQ + n0 + r) * C_DIM + h * 64 + e0;
    short4v H = {(short)f2bf(acc.x * Z), (short)f2bf(acc.y * Z),
                 (short)f2bf(acc.z * Z), (short)f2bf(acc.w * Z)};
    *(short4v*)&O1[off] = H;
}

extern "C" void kernel_launch(void* const* d_in, const int* in_sizes, int n_in,
                              void* d_out, int out_size, void* d_ws, size_t ws_size,
                              hipStream_t stream)
{
    const float* x   = (const float*)d_in[0];
    const float* Wq  = (const float*)d_in[1];
    const float* Wkv = (const float*)d_in[2];
    const float* Wo  = (const float*)d_in[3];
    const float* bo  = (const float*)d_in[4];
    float* out = (float*)d_out;

    float* ws    = (float*)d_ws;
    ushort* QKVu = (ushort*)ws;                        // 4096*3072 bf16 (24 MB)
    float* KVp   = ws + (size_t)M_ROWS * 3072 / 2;     // 8*32*4160 f32
    float* KVf   = KVp + (size_t)8 * 32 * 4160;        // 32*4160
    ushort* xhi  = (ushort*)(KVf + 32 * 4160);         // 4096*1024 bf16
    ushort* Whi  = xhi + (size_t)M_ROWS * 1024;        // 3072*1024 (Wq;Wkv)
    ushort* Wohi = Whi + (size_t)3072 * 1024;          // 1024*1024
    ushort* O1   = xhi;                                // alias: x dead after GEMM1

    hipFuncSetAttribute((const void*)gemm1_kernel,
                        hipFuncAttributeMaxDynamicSharedMemorySize, 81920);

    // 0. fp32 -> bf16 conversions
    split_all_kernel<<<dim3(4096), 256, 0, stream>>>(
        x, Wq, Wkv, Wo, xhi, Whi, Wohi);

    // 1. fused q/k/v projections, single-term bf16, bf16 output
    gemm1_kernel<<<dim3(512), 256, 81920, stream>>>(xhi, Whi, QKVu);

    // 2-3. KV = K^T V + ksum (8-way split + deterministic reduce)
    kv_partial_kernel<<<dim3(32, 8), 256, 0, stream>>>(QKVu, KVp);
    kv_reduce_kernel<<<dim3((32 * 4160 + 255) / 256), 256, 0, stream>>>(KVp, KVf);

    // 4. O1 = Z * (q @ KV), bf16 out
    attn_apply_kernel<<<dim3(32, 128), 256, 0, stream>>>(QKVu, KVf, O1);

    // 5. final projection + bias (single-term bf16)
    gemm2_kernel<<<dim3(512), 256, 0, stream>>>(O1, Wohi, bo, out);
}

// Round 20
// 99.097 us; speedup vs baseline: 1.2998x; 1.0020x over previous
//
#include <hip/hip_runtime.h>
#include <math.h>

#define C_DIM 1024
#define B_SZ 2
#define N_SEQ 2048
#define M_ROWS (B_SZ * N_SEQ)   // 4096
#define KDIM 1024
#define G1_SLOT 10240           // ushorts per 20KB gemm1 slot (A 8KB + B 12KB)
#define G2_SLOT 6144            // ushorts per 12KB gemm2 slot (A 4KB + B 8KB)

typedef float  f32x4   __attribute__((ext_vector_type(4)));
typedef short  bf16x8  __attribute__((ext_vector_type(8)));
typedef short  short4v __attribute__((ext_vector_type(4)));
typedef short  short8v __attribute__((ext_vector_type(8)));

__device__ __forceinline__ float elu1(float v) {
    return v > 0.f ? v + 1.f : expf(v);
}

__device__ __forceinline__ ushort f2bf(float f) {
    union { float f; unsigned u; } x; x.f = f;
    unsigned r = (x.u + 0x7fffu + ((x.u >> 16) & 1u)) >> 16;  // RNE
    return (ushort)r;
}
__device__ __forceinline__ float bf2f(ushort b) {
    union { unsigned u; float f; } x; x.u = ((unsigned)b) << 16;
    return x.f;
}

#define VMCNT(n) asm volatile("s_waitcnt vmcnt(" #n ")" ::: "memory")
// Fence + barrier: all waves' outstanding LDS reads DELIVERED before any wave
// passes the barrier (compiler may sink MFMA lgkm waits past a raw s_barrier
// -> slot-overwrite race, R14 failure).
#define LGKMBAR do {                                                  \
        asm volatile("s_waitcnt lgkmcnt(0)" ::: "memory");            \
        __builtin_amdgcn_sched_barrier(0);                            \
        __builtin_amdgcn_s_barrier();                                 \
    } while (0)

__device__ __forceinline__ void gl16(const ushort* g, ushort* l) {
    __builtin_amdgcn_global_load_lds(
        (const __attribute__((address_space(1))) unsigned int*)g,
        (__attribute__((address_space(3))) unsigned int*)l,
        16, 0, 0);
}

// ---------------------------------------------------------------------------
// fp32 -> bf16 (hi only, RNE) for x, [Wq;Wkv], Wo. 8 elems/thread.
// ---------------------------------------------------------------------------
__global__ __launch_bounds__(256)
void split_all_kernel(const float* __restrict__ x, const float* __restrict__ Wq,
                      const float* __restrict__ Wkv, const float* __restrict__ Wo,
                      ushort* __restrict__ xhi, ushort* __restrict__ Whi,
                      ushort* __restrict__ Wohi)
{
    const int i = blockIdx.x * 256 + threadIdx.x;   // 0..1048575
    const float* src; ushort* dh; int off;
    if (i < 524288)        { src = x;   dh = xhi;  off = i; }
    else if (i < 655360)   { src = Wq;  dh = Whi;  off = i - 524288; }
    else if (i < 917504)   { src = Wkv; dh = Whi + (1u << 20); off = i - 655360; }
    else                   { src = Wo;  dh = Wohi; off = i - 917504; }

    const float4 a = ((const float4*)src)[off * 2];
    const float4 b = ((const float4*)src)[off * 2 + 1];
    const float v[8] = {a.x, a.y, a.z, a.w, b.x, b.y, b.z, b.w};
    ushort hv[8];
    #pragma unroll
    for (int j = 0; j < 8; ++j) hv[j] = f2bf(v[j]);
    short8v H = {(short)hv[0],(short)hv[1],(short)hv[2],(short)hv[3],
                 (short)hv[4],(short)hv[5],(short)hv[6],(short)hv[7]};
    *(short8v*)&dh[(size_t)off * 8] = H;
}

// ---------------------------------------------------------------------------
// GEMM1: QKV(bf16) = x @ [Wq;Wkv]^T (3072 cols), single-term bf16.
// 128x192 tile, BK=32, 4 waves (2x2), wave 64x96. Grid 512 -> 2 blocks/CU
// (80KB). 1 LGKMBAR/kt, 4-slot rotation, depth-3 (vmcnt(10); edges 5/0).
// XCD swizzle: 8m x 8n rectangle per XCD. elu1 on cols<2048; V raw.
// ---------------------------------------------------------------------------
__global__ __launch_bounds__(256, 2)
void gemm1_kernel(const ushort* __restrict__ Ahi, const ushort* __restrict__ Bhi,
                  ushort* __restrict__ dst)
{
    extern __shared__ ushort smem[];   // 4 slots x 10240 ushorts (80 KB)

    const int bid = blockIdx.x;
    const int r   = bid & 7;           // XCD (round-robin dispatch)
    const int ii  = bid >> 3;          // 0..63 within XCD
    const int m0  = ((r >> 1) * 8 + (ii >> 3)) * 128;   // 32 m-tiles
    const int n0  = ((r & 1) * 8 + (ii & 7)) * 192;     // 16 n-tiles

    const int t    = threadIdx.x;
    const int lane = t & 63;
    const int w    = t >> 6;       // 0..3
    const int wr   = w >> 1;       // 0..1  (M half, 64 rows)
    const int wc   = w & 1;        // 0..1  (N half, 96 cols)

    const int gch     = (t & 3) ^ ((t >> 3) & 3);
    const size_t rowA  = (size_t)(m0 + (t >> 2)) * KDIM + gch * 8;   // A rows 0..63
    const size_t rowA2 = rowA + (size_t)64 * KDIM;                   // 64..127
    const size_t rowB  = (size_t)(n0 + (t >> 2)) * KDIM + gch * 8;   // B rows 0..63
    const size_t rowB2 = rowB + (size_t)64 * KDIM;                   // 64..127
    const size_t rowB3 = rowB + (size_t)128 * KDIM;                  // 128..191
    const int wl      = w * 512;

    const int frow = lane & 15;
    const int cc   = (lane >> 4) ^ ((lane >> 1) & 3);
    const int aoff = (wr * 64 + frow) * 32 + cc * 8;
    const int boff = 4096 + (wc * 96 + frow) * 32 + cc * 8;

    f32x4 acc[4][6];
    #pragma unroll
    for (int mi = 0; mi < 4; ++mi)
        #pragma unroll
        for (int nj = 0; nj < 6; ++nj)
            acc[mi][nj] = (f32x4){0.f, 0.f, 0.f, 0.f};

    #define STAGE1(slotp, koff)                                              \
        do {                                                                 \
            ushort* sl_ = (slotp);                                           \
            gl16(Ahi + rowA  + (koff), sl_ + wl);                            \
            gl16(Ahi + rowA2 + (koff), sl_ + 2048 + wl);                     \
            gl16(Bhi + rowB  + (koff), sl_ + 4096 + wl);                     \
            gl16(Bhi + rowB2 + (koff), sl_ + 6144 + wl);                     \
            gl16(Bhi + rowB3 + (koff), sl_ + 8192 + wl);                     \
        } while (0)

    // prologue: kt0->slot0, kt1->slot1, kt2->slot2  (15 loads in flight)
    STAGE1(smem, 0);
    STAGE1(smem + G1_SLOT, 32);
    STAGE1(smem + 2 * G1_SLOT, 64);

    #pragma unroll 1
    for (int kt = 0; kt < 32; ++kt) {
        ushort* sh = smem + (kt & 3) * G1_SLOT;

        if (kt <= 29) { VMCNT(10); } else if (kt == 30) { VMCNT(5); } else { VMCNT(0); }
        LGKMBAR;   // all waves' kt-1 reads DELIVERED before slot reuse
        if (kt <= 28) STAGE1(smem + ((kt + 3) & 3) * G1_SLOT, (kt + 3) * 32);

        bf16x8 ah[4], bh[6];
        #pragma unroll
        for (int mi = 0; mi < 4; ++mi)
            ah[mi] = *(const bf16x8*)(sh + aoff + mi * 512);
        #pragma unroll
        for (int nj = 0; nj < 6; ++nj)
            bh[nj] = *(const bf16x8*)(sh + boff + nj * 512);
        __builtin_amdgcn_s_setprio(1);
        #pragma unroll
        for (int mi = 0; mi < 4; ++mi)
            #pragma unroll
            for (int nj = 0; nj < 6; ++nj)
                acc[mi][nj] = __builtin_amdgcn_mfma_f32_16x16x32_bf16(
                    ah[mi], bh[nj], acc[mi][nj], 0, 0, 0);
        __builtin_amdgcn_s_setprio(0);
    }
    #undef STAGE1

    const int erow  = m0 + wr * 64 + (lane >> 4) * 4;
    const int ecol0 = n0 + wc * 96 + frow;
    #pragma unroll
    for (int mi = 0; mi < 4; ++mi) {
        #pragma unroll
        for (int j = 0; j < 4; ++j) {
            const int row = erow + mi * 16 + j;
            #pragma unroll
            for (int nj = 0; nj < 6; ++nj) {
                const int col = ecol0 + nj * 16;
                float v = acc[mi][nj][j];
                if (col < 2048) v = elu1(v);   // Q,K get elu1; V raw
                dst[(size_t)row * 3072 + col] = f2bf(v);
            }
        }
    }
}

// ---------------------------------------------------------------------------
// GEMM2: out = O1 @ Wo^T + bo, single-term bf16. 64x128 tile, BK=32,
// 4 waves (1M x 4N), wave 64x32. Grid 512 -> 2 blocks/CU (48KB).
// 1 LGKMBAR/kt, 4-slot rotation, depth-3 (vmcnt(6); edges 3/0).
// ---------------------------------------------------------------------------
__global__ __launch_bounds__(256, 2)
void gemm2_kernel(const ushort* __restrict__ O1, const ushort* __restrict__ Wo,
                  const float* __restrict__ bias, float* __restrict__ dst)
{
    __shared__ ushort smem[4 * G2_SLOT];   // 48 KB

    const int bid = blockIdx.x;
    const int wg  = (bid & 7) * 64 + (bid >> 3);    // bijective: 512 = 8*64
    const int m0  = (wg >> 3) * 64;                 // 64 m-tiles
    const int n0  = (wg & 7) * 128;                 // 8 n-tiles

    const int t    = threadIdx.x;
    const int lane = t & 63;
    const int w    = t >> 6;      // 0..3 (N quarters, 32 cols)

    const int gch     = (t & 3) ^ ((t >> 3) & 3);
    const size_t rowA  = (size_t)(m0 + (t >> 2)) * KDIM + gch * 8;   // 64 rows
    const size_t rowB  = (size_t)(n0 + (t >> 2)) * KDIM + gch * 8;   // rows 0..63
    const size_t rowB2 = rowB + (size_t)64 * KDIM;                   // 64..127
    const int wl      = w * 512;

    const int frow = lane & 15;
    const int cc   = (lane >> 4) ^ ((lane >> 1) & 3);
    const int aoff = frow * 32 + cc * 8;
    const int boff = 2048 + (w * 32 + frow) * 32 + cc * 8;

    f32x4 acc[4][2];
    #pragma unroll
    for (int mi = 0; mi < 4; ++mi)
        #pragma unroll
        for (int nj = 0; nj < 2; ++nj)
            acc[mi][nj] = (f32x4){0.f, 0.f, 0.f, 0.f};

    #define STAGE2(slotp, koff)                                              \
        do {                                                                 \
            ushort* p_ = (slotp);                                            \
            gl16(O1 + rowA  + (koff), p_ + wl);                              \
            gl16(Wo + rowB  + (koff), p_ + 2048 + wl);                       \
            gl16(Wo + rowB2 + (koff), p_ + 4096 + wl);                       \
        } while (0)

    // prologue: kt0->slot0, kt1->slot1, kt2->slot2  (9 loads in flight)
    STAGE2(smem, 0);
    STAGE2(smem + G2_SLOT, 32);
    STAGE2(smem + 2 * G2_SLOT, 64);

    #pragma unroll 1
    for (int kt = 0; kt < 32; ++kt) {
        ushort* sh = smem + (kt & 3) * G2_SLOT;

        if (kt <= 29) { VMCNT(6); } else if (kt == 30) { VMCNT(3); } else { VMCNT(0); }
        LGKMBAR;
        if (kt <= 28) STAGE2(smem + ((kt + 3) & 3) * G2_SLOT, (kt + 3) * 32);

        bf16x8 ah[4], bh[2];
        #pragma unroll
        for (int mi = 0; mi < 4; ++mi)
            ah[mi] = *(const bf16x8*)(sh + aoff + mi * 512);
        #pragma unroll
        for (int nj = 0; nj < 2; ++nj)
            bh[nj] = *(const bf16x8*)(sh + boff + nj * 512);
        __builtin_amdgcn_s_setprio(1);
        #pragma unroll
        for (int mi = 0; mi < 4; ++mi)
            #pragma unroll
            for (int nj = 0; nj < 2; ++nj)
                acc[mi][nj] = __builtin_amdgcn_mfma_f32_16x16x32_bf16(
                    ah[mi], bh[nj], acc[mi][nj], 0, 0, 0);
        __builtin_amdgcn_s_setprio(0);
    }
    #undef STAGE2

    const int erow  = m0 + (lane >> 4) * 4;
    const int ecol0 = n0 + w * 32 + frow;
    #pragma unroll
    for (int mi = 0; mi < 4; ++mi) {
        #pragma unroll
        for (int j = 0; j < 4; ++j) {
            const int row = erow + mi * 16 + j;
            #pragma unroll
            for (int nj = 0; nj < 2; ++nj) {
                const int col = ecol0 + nj * 16;
                dst[(size_t)row * 1024 + col] = acc[mi][nj][j] + bias[col];
            }
        }
    }
}

// ---------------------------------------------------------------------------
// Partial KV = K_feat^T V and ksum, per (b,h), 8-way N split (256 rows each).
// QKV bf16: stage short4v, convert to f32 in LDS; compute f32.
// ---------------------------------------------------------------------------
__global__ __launch_bounds__(256)
void kv_partial_kernel(const ushort* __restrict__ QKV, float* __restrict__ KVp)
{
    const int bh = blockIdx.x;   // 0..31
    const int s  = blockIdx.y;   // 0..7
    const int b  = bh >> 4;
    const int h  = bh & 15;
    const int t  = threadIdx.x;

    __shared__ float ks[16][64];
    __shared__ float vs[16][64];
    __shared__ float red[4160];

    const int srow = t >> 4;
    const int scol = (t & 15) * 4;
    const size_t gk = (size_t)(b * N_SEQ + s * 256) * 3072 + 1024 + h * 64 + scol;
    const size_t gv = gk + 1024;

    const int rs = t >> 6;
    const int dg = (t >> 3) & 7;
    const int eg = t & 7;
    const int d0 = dg * 8;
    const int e0 = eg * 8;

    float acc[8][8];
    #pragma unroll
    for (int i = 0; i < 8; ++i)
        #pragma unroll
        for (int j = 0; j < 8; ++j) acc[i][j] = 0.f;
    float aks[8] = {0.f, 0.f, 0.f, 0.f, 0.f, 0.f, 0.f, 0.f};

    short4v kr = *(const short4v*)&QKV[gk + (size_t)srow * 3072];
    short4v vr = *(const short4v*)&QKV[gv + (size_t)srow * 3072];

    for (int it = 0; it < 16; ++it) {
        __syncthreads();
        ks[srow][scol + 0] = bf2f((ushort)kr[0]);
        ks[srow][scol + 1] = bf2f((ushort)kr[1]);
        ks[srow][scol + 2] = bf2f((ushort)kr[2]);
        ks[srow][scol + 3] = bf2f((ushort)kr[3]);
        vs[srow][scol + 0] = bf2f((ushort)vr[0]);
        vs[srow][scol + 1] = bf2f((ushort)vr[1]);
        vs[srow][scol + 2] = bf2f((ushort)vr[2]);
        vs[srow][scol + 3] = bf2f((ushort)vr[3]);
        __syncthreads();
        if (it < 15) {
            kr = *(const short4v*)&QKV[gk + (size_t)((it + 1) * 16 + srow) * 3072];
            vr = *(const short4v*)&QKV[gv + (size_t)((it + 1) * 16 + srow) * 3072];
        }
        #pragma unroll
        for (int rr = 0; rr < 4; ++rr) {
            const int r = rs * 4 + rr;
            const float4 ka = *(const float4*)&ks[r][d0];
            const float4 kb = *(const float4*)&ks[r][d0 + 4];
            const float4 va = *(const float4*)&vs[r][e0];
            const float4 vb = *(const float4*)&vs[r][e0 + 4];
            const float k8[8] = {ka.x, ka.y, ka.z, ka.w, kb.x, kb.y, kb.z, kb.w};
            const float v8[8] = {va.x, va.y, va.z, va.w, vb.x, vb.y, vb.z, vb.w};
            #pragma unroll
            for (int i = 0; i < 8; ++i)
                #pragma unroll
                for (int j = 0; j < 8; ++j)
                    acc[i][j] += k8[i] * v8[j];
            if (eg == 0) {
                #pragma unroll
                for (int i = 0; i < 8; ++i) aks[i] += k8[i];
            }
        }
    }

    #pragma unroll 1
    for (int step = 1; step < 4; ++step) {
        __syncthreads();
        if (rs == step) {
            #pragma unroll
            for (int i = 0; i < 8; ++i)
                #pragma unroll
                for (int j = 0; j < 8; ++j)
                    red[(d0 + i) * 64 + e0 + j] = acc[i][j];
            if (eg == 0) {
                #pragma unroll
                for (int i = 0; i < 8; ++i) red[4096 + d0 + i] = aks[i];
            }
        }
        __syncthreads();
        if (rs == 0) {
            #pragma unroll
            for (int i = 0; i < 8; ++i)
                #pragma unroll
                for (int j = 0; j < 8; ++j)
                    acc[i][j] += red[(d0 + i) * 64 + e0 + j];
            if (eg == 0) {
                #pragma unroll
                for (int i = 0; i < 8; ++i) aks[i] += red[4096 + d0 + i];
            }
        }
    }

    if (rs == 0) {
        float* outp = KVp + ((size_t)s * 32 + bh) * 4160;
        #pragma unroll
        for (int i = 0; i < 8; ++i) {
            float4 o0 = {acc[i][0], acc[i][1], acc[i][2], acc[i][3]};
            float4 o1 = {acc[i][4], acc[i][5], acc[i][6], acc[i][7]};
            *(float4*)(outp + (d0 + i) * 64 + e0)     = o0;
            *(float4*)(outp + (d0 + i) * 64 + e0 + 4) = o1;
        }
        if (eg == 0) {
            #pragma unroll
            for (int i = 0; i < 8; ++i) outp[4096 + d0 + i] = aks[i];
        }
    }
}

__global__ __launch_bounds__(256)
void kv_reduce_kernel(const float* __restrict__ KVp, float* __restrict__ KVf)
{
    const int idx = blockIdx.x * 256 + threadIdx.x;
    if (idx < 32 * 4160) {
        float s = 0.f;
        #pragma unroll
        for (int i = 0; i < 8; ++i) s += KVp[(size_t)i * (32 * 4160) + idx];
        KVf[idx] = s;
    }
}

// ---------------------------------------------------------------------------
// O1[n, h*64+e] = Z * sum_d q[n,d]*KV[d,e], Z = 1/(q.ksum + 1e-6).
// 64 q-rows per block (grid 32 x 32): KV state loaded into LDS ONCE, then
// 4 row-groups of 16 processed in a loop (4x less KVf re-read vs R19).
// Numerics identical to R19 (same per-row dot products).
// ---------------------------------------------------------------------------
__global__ __launch_bounds__(256)
void attn_apply_kernel(const ushort* __restrict__ QKV, const float* __restrict__ KVf,
                       ushort* __restrict__ O1)
{
    const int bh = blockIdx.x;
    const int b = bh >> 4, h = bh & 15;
    const int nbase = blockIdx.y * 64;
    const int t = threadIdx.x;
    const int r  = t >> 4;           // 0..15 (row within group)
    const int e0 = (t & 15) * 4;

    __shared__ float kvs[64][68];
    __shared__ float qs[16][68];
    __shared__ float ksums[64];

    const float* kvb = KVf + (size_t)bh * 4160;
    for (int i = t; i < 4096; i += 256)
        kvs[i >> 6][i & 63] = kvb[i];
    if (t < 64) ksums[t] = kvb[4096 + t];

    #pragma unroll 1
    for (int rg = 0; rg < 4; ++rg) {
        const int n0 = nbase + rg * 16;
        __syncthreads();   // guard qs overwrite (and first-iter kvs fill)
        {
            const int rr = t >> 4, cc2 = (t & 15) * 4;
            short4v q4 = *(const short4v*)&QKV[(size_t)(b * N_SEQ + n0 + rr) * 3072 + h * 64 + cc2];
            qs[rr][cc2 + 0] = bf2f((ushort)q4[0]);
            qs[rr][cc2 + 1] = bf2f((ushort)q4[1]);
            qs[rr][cc2 + 2] = bf2f((ushort)q4[2]);
            qs[rr][cc2 + 3] = bf2f((ushort)q4[3]);
        }
        __syncthreads();

        float4 acc = {0.f, 0.f, 0.f, 0.f};
        float accz = 0.f;
        #pragma unroll
        for (int d = 0; d < 64; ++d) {
            const float qv = qs[r][d];
            const float4 kvv = *(const float4*)&kvs[d][e0];
            acc.x += qv * kvv.x; acc.y += qv * kvv.y;
            acc.z += qv * kvv.z; acc.w += qv * kvv.w;
            accz += qv * ksums[d];
        }
        const float Z = 1.f / (accz + 1e-6f);
        const size_t off = (size_t)(b * N_SEQ + n0 + r) * C_DIM + h * 64 + e0;
        short4v H = {(short)f2bf(acc.x * Z), (short)f2bf(acc.y * Z),
                     (short)f2bf(acc.z * Z), (short)f2bf(acc.w * Z)};
        *(short4v*)&O1[off] = H;
    }
}

extern "C" void kernel_launch(void* const* d_in, const int* in_sizes, int n_in,
                              void* d_out, int out_size, void* d_ws, size_t ws_size,
                              hipStream_t stream)
{
    const float* x   = (const float*)d_in[0];
    const float* Wq  = (const float*)d_in[1];
    const float* Wkv = (const float*)d_in[2];
    const float* Wo  = (const float*)d_in[3];
    const float* bo  = (const float*)d_in[4];
    float* out = (float*)d_out;

    float* ws    = (float*)d_ws;
    ushort* QKVu = (ushort*)ws;                        // 4096*3072 bf16 (24 MB)
    float* KVp   = ws + (size_t)M_ROWS * 3072 / 2;     // 8*32*4160 f32
    float* KVf   = KVp + (size_t)8 * 32 * 4160;        // 32*4160
    ushort* xhi  = (ushort*)(KVf + 32 * 4160);         // 4096*1024 bf16
    ushort* Whi  = xhi + (size_t)M_ROWS * 1024;        // 3072*1024 (Wq;Wkv)
    ushort* Wohi = Whi + (size_t)3072 * 1024;          // 1024*1024
    ushort* O1   = xhi;                                // alias: x dead after GEMM1

    hipFuncSetAttribute((const void*)gemm1_kernel,
                        hipFuncAttributeMaxDynamicSharedMemorySize, 81920);

    // 0. fp32 -> bf16 conversions
    split_all_kernel<<<dim3(4096), 256, 0, stream>>>(
        x, Wq, Wkv, Wo, xhi, Whi, Wohi);

    // 1. fused q/k/v projections, single-term bf16, bf16 output
    gemm1_kernel<<<dim3(512), 256, 81920, stream>>>(xhi, Whi, QKVu);

    // 2-3. KV = K^T V + ksum (8-way split + deterministic reduce)
    kv_partial_kernel<<<dim3(32, 8), 256, 0, stream>>>(QKVu, KVp);
    kv_reduce_kernel<<<dim3((32 * 4160 + 255) / 256), 256, 0, stream>>>(KVp, KVf);

    // 4. O1 = Z * (q @ KV), bf16 out (64 rows/block)
    attn_apply_kernel<<<dim3(32, 32), 256, 0, stream>>>(QKVu, KVf, O1);

    // 5. final projection + bias (single-term bf16)
    gemm2_kernel<<<dim3(512), 256, 0, stream>>>(O1, Wohi, bo, out);
}